// Round 8
// baseline (323.186 us; speedup 1.0000x reference)
//
#include <hip/hip_runtime.h>
#include <math.h>

// MaskedBalancedBCELoss — hard-negative mining via count-histogram select.
//
// R18: VERBATIM transplant of the R16-fast k1b_cand structure into the real
// k1. R17 post-mortem: promoting only the branchless atomic did NOT
// reproduce k1b's 24.7us/pass (k1 stuck at 70.8us, VALUBusy 9.4%, L3-warm
// replays equally slow). Remaining deltas between fast-k1b and slow-k1:
//   (1) outer rep loop around the grid-stride loop (kept: runtime nrep=1,
//       so the loop nest survives codegen),
//   (2) materialized pa/ga/ma[16] arrays (one vmcnt-wait for all 12 loads,
//       then a 16-wide unrolled body),
//   (3) light epilogue (per-wave global atomics, no LDS-staged reduce),
//   (4) no remainder/tail in k1b (ours kept, provably-disjoint, cold).
// Diagnostic dg_kb1 = k1b_cand with compile-time AREP=1 (light epilogue, no
// outer loop) on scratch -> decodes which delta mattered if k1 stays slow.
// k5 unchanged.

#define NBINS1 4096
#define K1_BLOCKS 1024

struct Ctrl {
  unsigned long long pos_cnt;
  unsigned long long neg_cnt;
  unsigned long long k;
  double pos_sum;
  unsigned B;
  unsigned k_rem;
};

#define LN2F 0.69314718055994530942f

__device__ __forceinline__ double bin_mid(unsigned b) {
  return (double)__uint_as_float((b << 19) | 0x40000u);
}

// Branchless per-element processing (loss bit-identical to R10..R17).
__device__ __forceinline__ void proc1(float p, float g, float m, unsigned ln,
                                      unsigned& pc, unsigned& nc,
                                      float& psumf, unsigned* __restrict__ hc) {
  bool gpos = (g != 0.0f);
  bool valid = (m != 0.0f);
  bool ispos = valid && gpos;
  bool isneg = valid && !gpos;
  float x = gpos ? p : 1.0f - p;
  float loss = -fmaxf(__log2f(x) * LN2F, -100.0f);
  pc += ispos ? 1u : 0u;
  nc += isneg ? 1u : 0u;
  psumf += ispos ? loss : 0.0f;
  unsigned b = isneg ? (__float_as_uint(loss) >> 19) : (NBINS1 + ln);
  atomicAdd(&hc[b], 1u);
}

// ---------------- Kernel 1: reductions + level-1 histogram -----------------
// Hot loop is a literal copy of R16 k1b_cand (measured 24.7us/pass).
extern "C" __global__ void __launch_bounds__(256, 4)
k1_hist(const float* __restrict__ pred, const float* __restrict__ gt,
        const float* __restrict__ mask, unsigned* __restrict__ hist1,
        Ctrl* __restrict__ ctrl, int n4, int n, int nrep) {
  __shared__ unsigned h[NBINS1 + 64];
  for (int i = threadIdx.x; i < NBINS1 + 64; i += blockDim.x) h[i] = 0u;
  __syncthreads();

  const float4* p4 = (const float4*)pred;
  const float4* g4 = (const float4*)gt;
  const float4* m4 = (const float4*)mask;
  int gtid = blockIdx.x * blockDim.x + threadIdx.x;
  int S = gridDim.x * blockDim.x;
  unsigned ln = threadIdx.x & 63;

  unsigned pc = 0, nc = 0;
  float psumf = 0.0f;
  for (int rep = 0; rep < nrep; ++rep) {
    for (int i = gtid; i + 3 * S + nrep < n4; i += 4 * S) {
      int jb = i + rep;
      float4 pv0 = p4[jb], pv1 = p4[jb + S], pv2 = p4[jb + 2 * S], pv3 = p4[jb + 3 * S];
      float4 gv0 = g4[jb], gv1 = g4[jb + S], gv2 = g4[jb + 2 * S], gv3 = g4[jb + 3 * S];
      float4 mv0 = m4[jb], mv1 = m4[jb + S], mv2 = m4[jb + 2 * S], mv3 = m4[jb + 3 * S];
      float pa[16] = {pv0.x, pv0.y, pv0.z, pv0.w, pv1.x, pv1.y, pv1.z, pv1.w,
                      pv2.x, pv2.y, pv2.z, pv2.w, pv3.x, pv3.y, pv3.z, pv3.w};
      float ga[16] = {gv0.x, gv0.y, gv0.z, gv0.w, gv1.x, gv1.y, gv1.z, gv1.w,
                      gv2.x, gv2.y, gv2.z, gv2.w, gv3.x, gv3.y, gv3.z, gv3.w};
      float ma[16] = {mv0.x, mv0.y, mv0.z, mv0.w, mv1.x, mv1.y, mv1.z, mv1.w,
                      mv2.x, mv2.y, mv2.z, mv2.w, mv3.x, mv3.y, mv3.z, mv3.w};
#pragma unroll
      for (int j = 0; j < 16; j++) {
        bool gpos = (ga[j] != 0.0f);
        bool valid = (ma[j] != 0.0f);
        bool ispos = valid && gpos;
        bool isneg = valid && !gpos;
        float x = gpos ? pa[j] : 1.0f - pa[j];
        float loss = -fmaxf(__log2f(x) * LN2F, -100.0f);
        pc += ispos ? 1u : 0u;
        nc += isneg ? 1u : 0u;
        psumf += ispos ? loss : 0.0f;
        unsigned b = isneg ? (__float_as_uint(loss) >> 19) : (NBINS1 + ln);
        atomicAdd(&h[b], 1u);   // unconditional: no exec-mask branch
      }
    }
  }

  // ---- cold coverage completion (nrep==1 in production) ----
  // main nest covered {j = gtid + k*S : gtid <= j < idone}; finish the rest.
  int idone = gtid;
  while (idone + 3 * S + nrep < n4) idone += 4 * S;
  for (int i = idone; i < n4; i += S) {
    float4 pv = p4[i], gv = g4[i], mv = m4[i];
    proc1(pv.x, gv.x, mv.x, ln, pc, nc, psumf, h);
    proc1(pv.y, gv.y, mv.y, ln, pc, nc, psumf, h);
    proc1(pv.z, gv.z, mv.z, ln, pc, nc, psumf, h);
    proc1(pv.w, gv.w, mv.w, ln, pc, nc, psumf, h);
  }
  for (int t = n4 * 4 + gtid; t < n; t += S) {
    proc1(pred[t], gt[t], mask[t], ln, pc, nc, psumf, h);
  }

  // ---- light epilogue (k1b-shaped): wave reduce -> per-wave global atomics
  unsigned long long pcl = pc, ncl = nc;
  double psum = (double)psumf;
  for (int off = 32; off > 0; off >>= 1) {
    pcl += __shfl_down(pcl, off);
    ncl += __shfl_down(ncl, off);
    psum += __shfl_down(psum, off);
  }
  if (ln == 0) {
    atomicAdd(&ctrl->pos_cnt, pcl);
    atomicAdd(&ctrl->neg_cnt, ncl);
    unsafeAtomicAdd(&ctrl->pos_sum, psum);
  }
  __syncthreads();   // all LDS histogram atomics complete
  // flush LDS histogram to global (dummy bins >= NBINS1 ignored)
  for (int b = threadIdx.x; b < NBINS1; b += blockDim.x) {
    unsigned c = h[b];
    if (c) atomicAdd(&hist1[b], c);
  }
}

// ---------- Kernel 5: select + midpoint neg_sum + output (1 block) ---------
extern "C" __global__ void __launch_bounds__(256)
k5_final(const unsigned* __restrict__ hist1, Ctrl* __restrict__ ctrl,
         float* __restrict__ out) {
  const int T = 256, CH = NBINS1 / T;  // 16 bins per thread
  __shared__ unsigned long long sarr[T];
  __shared__ unsigned long long sk;
  __shared__ unsigned sB, skrem;
  __shared__ double sred[4];
  int t = threadIdx.x;
  int wv = t >> 6, ln = t & 63;

  unsigned cnt[CH];
  unsigned long long tot = 0;
  for (int j = 0; j < CH; j++) { cnt[j] = hist1[t * CH + j]; tot += cnt[j]; }
  sarr[t] = tot;
  if (t == 0) {
    sB = 0xFFFFFFFFu; skrem = 0u;
    unsigned long long pos = ctrl->pos_cnt, negtot = ctrl->neg_cnt;
    unsigned long long k = 0;
    if (pos > 0) {               // FALLBACK_NEG=0 when pos==0
      k = pos * 3ull;            // floor(pos*3.0), exact in integer
      if (k > negtot) k = negtot;
    }
    ctrl->k = k;
    sk = k;
  }
  __syncthreads();
  // inclusive suffix scan: sarr[t] = sum over threads >= t
  for (int off = 1; off < T; off <<= 1) {
    unsigned long long v = (t + off < T) ? sarr[t + off] : 0ull;
    __syncthreads();
    sarr[t] += v;
    __syncthreads();
  }
  unsigned long long k = sk;
  if (k > 0) {
    unsigned long long above = sarr[t] - tot;
    if (above < k && sarr[t] >= k) {
      unsigned long long cum = above;
      for (int j = CH - 1; j >= 0; j--) {
        if (cum + (unsigned long long)cnt[j] >= k) {
          sB = (unsigned)(t * CH + j);
          skrem = (unsigned)(k - cum);
          break;
        }
        cum += cnt[j];
      }
    }
  }
  __syncthreads();
  unsigned B = sB;

  double s = 0.0;
  if (B != 0xFFFFFFFFu) {
    for (int j = 0; j < CH; j++) {
      unsigned bi = (unsigned)(t * CH + j);
      if (bi > B && cnt[j]) s += (double)cnt[j] * bin_mid(bi);
    }
  }
  for (int off = 32; off > 0; off >>= 1) s += __shfl_down(s, off);
  if (ln == 0) sred[wv] = s;
  __syncthreads();
  if (t == 0) {
    double neg_sum = sred[0] + sred[1] + sred[2] + sred[3];
    if (skrem > 0 && B != 0xFFFFFFFFu)
      neg_sum += (double)skrem * bin_mid(B);
    double denom = (double)ctrl->pos_cnt + (double)k + 1e-6;
    out[0] = (float)((ctrl->pos_sum + neg_sum) / denom);
  }
}

// ---- dg_kb1: R16 k1b_cand with compile-time AREP=1 (diagnostic, scratch) --
extern "C" __global__ void __launch_bounds__(256, 4)
dg_kb1(const float* __restrict__ pred, const float* __restrict__ gt,
       const float* __restrict__ mask, unsigned* __restrict__ shist,
       float* __restrict__ scratch, int n4) {
  __shared__ unsigned h[NBINS1 + 64];
  for (int i = threadIdx.x; i < NBINS1 + 64; i += blockDim.x) h[i] = 0u;
  __syncthreads();

  const float4* p4 = (const float4*)pred;
  const float4* g4 = (const float4*)gt;
  const float4* m4 = (const float4*)mask;
  int gtid = blockIdx.x * blockDim.x + threadIdx.x;
  int S = gridDim.x * blockDim.x;
  unsigned ln = threadIdx.x & 63;

  unsigned pc = 0, nc = 0;
  float psumf = 0.0f;
  for (int rep = 0; rep < 1; ++rep) {
    for (int i = gtid; i + 3 * S + 1 < n4; i += 4 * S) {
      int jb = i + rep;
      float4 pv0 = p4[jb], pv1 = p4[jb + S], pv2 = p4[jb + 2 * S], pv3 = p4[jb + 3 * S];
      float4 gv0 = g4[jb], gv1 = g4[jb + S], gv2 = g4[jb + 2 * S], gv3 = g4[jb + 3 * S];
      float4 mv0 = m4[jb], mv1 = m4[jb + S], mv2 = m4[jb + 2 * S], mv3 = m4[jb + 3 * S];
      float pa[16] = {pv0.x, pv0.y, pv0.z, pv0.w, pv1.x, pv1.y, pv1.z, pv1.w,
                      pv2.x, pv2.y, pv2.z, pv2.w, pv3.x, pv3.y, pv3.z, pv3.w};
      float ga[16] = {gv0.x, gv0.y, gv0.z, gv0.w, gv1.x, gv1.y, gv1.z, gv1.w,
                      gv2.x, gv2.y, gv2.z, gv2.w, gv3.x, gv3.y, gv3.z, gv3.w};
      float ma[16] = {mv0.x, mv0.y, mv0.z, mv0.w, mv1.x, mv1.y, mv1.z, mv1.w,
                      mv2.x, mv2.y, mv2.z, mv2.w, mv3.x, mv3.y, mv3.z, mv3.w};
#pragma unroll
      for (int j = 0; j < 16; j++) {
        bool gpos = (ga[j] != 0.0f);
        bool valid = (ma[j] != 0.0f);
        bool ispos = valid && gpos;
        bool isneg = valid && !gpos;
        float x = gpos ? pa[j] : 1.0f - pa[j];
        float loss = -fmaxf(__log2f(x) * LN2F, -100.0f);
        pc += ispos ? 1u : 0u;
        nc += isneg ? 1u : 0u;
        psumf += ispos ? loss : 0.0f;
        unsigned b = isneg ? (__float_as_uint(loss) >> 19) : (NBINS1 + ln);
        atomicAdd(&h[b], 1u);
      }
    }
  }
  float s = psumf + (float)pc + (float)nc;
  for (int off = 32; off > 0; off >>= 1) s += __shfl_down(s, off);
  if ((threadIdx.x & 63) == 0)
    scratch[blockIdx.x * 4 + (threadIdx.x >> 6)] = s;
  __syncthreads();
  for (int b = threadIdx.x; b < NBINS1; b += blockDim.x) {
    unsigned c = h[b];
    if (c) atomicAdd(&shist[b], c);
  }
}

// ---------------------------------------------------------------------------
extern "C" void kernel_launch(void* const* d_in, const int* in_sizes, int n_in,
                              void* d_out, int out_size, void* d_ws, size_t ws_size,
                              hipStream_t stream) {
  const float* pred = (const float*)d_in[0];
  const float* gt   = (const float*)d_in[1];
  const float* mask = (const float*)d_in[2];
  float* out = (float*)d_out;
  int n = in_sizes[0];
  int n4 = n / 4;
  char* ws = (char*)d_ws;

  // layout: ctrl@0 (64B), hist1@256 (16KB) -> zero first 16640 bytes
  const size_t HIST1_OFF = 256;
  const size_t ZERO_BYTES = HIST1_OFF + NBINS1 * sizeof(unsigned);   // 16640
  const size_t DG_SCRATCH_OFF = 128 * 1024;
  const size_t DG_HIST_OFF = 192 * 1024;
  const size_t DG_END = 256 * 1024;

  Ctrl* ctrl = (Ctrl*)ws;
  unsigned* hist1 = (unsigned*)(ws + HIST1_OFF);

  hipMemsetAsync(d_ws, 0, ZERO_BYTES, stream);
  k1_hist<<<K1_BLOCKS, 256, 0, stream>>>(pred, gt, mask, hist1, ctrl, n4, n, 1);
  k5_final<<<1, 256, 0, stream>>>(hist1, ctrl, out);

  // within-probe A/B cell (scratch only; output unaffected)
  if (ws_size >= DG_END) {
    float* dgs = (float*)(ws + DG_SCRATCH_OFF);
    unsigned* dgh = (unsigned*)(ws + DG_HIST_OFF);
    dg_kb1<<<K1_BLOCKS, 256, 0, stream>>>(pred, gt, mask, dgh, dgs, n4);
  }
}

// Round 9
// 293.814 us; speedup vs baseline: 1.1000x; 1.1000x over previous
//
#include <hip/hip_runtime.h>
#include <math.h>

// MaskedBalancedBCELoss — hard-negative mining via count-histogram select.
//
// R19: promote the PROVEN-FAST structure with COMPILE-TIME bounds.
// Cross-round codegen ledger for the identical math:
//   R16 k1b_cand  (literal AREP=4, arrays, light epi)      : 24.7us/pass
//   R18 dg_kb1    (literal AREP=1, arrays, light epi)      : ~40us (censored-fast)
//   R18 k1        (RUNTIME nrep, arrays, tails, light epi) : 174us  <- poison
//   R17 k1        (no arrays, proc1-on-float4, tails)      : 70.8us
// Verdict: the fast schedule needs (a) compile-time loop bounds (runtime
// outer-loop var in address/bound kills it), (b) the materialized
// pa/ga/ma[16] arrays -> one vmcnt wait + 16-wide unrolled body, (c) the
// branchless unconditional atomic (R16's finding: the if(isneg) exec-mask
// dance was the original 75us wall).
// k1 here = dg_kb1 VERBATIM + cold remainder/tail coverage (branchless
// proc1, <=1 iter/thread) + light per-wave ctrl atomics + hist flush.
// No diagnostics this round. k5 unchanged.

#define NBINS1 4096
#define K1_BLOCKS 1024

struct Ctrl {
  unsigned long long pos_cnt;
  unsigned long long neg_cnt;
  unsigned long long k;
  double pos_sum;
  unsigned B;
  unsigned k_rem;
};

#define LN2F 0.69314718055994530942f

__device__ __forceinline__ double bin_mid(unsigned b) {
  return (double)__uint_as_float((b << 19) | 0x40000u);
}

// Branchless per-element processing (loss bit-identical to R10..R18).
__device__ __forceinline__ void proc1(float p, float g, float m, unsigned ln,
                                      unsigned& pc, unsigned& nc,
                                      float& psumf, unsigned* __restrict__ hc) {
  bool gpos = (g != 0.0f);
  bool valid = (m != 0.0f);
  bool ispos = valid && gpos;
  bool isneg = valid && !gpos;
  float x = gpos ? p : 1.0f - p;
  float loss = -fmaxf(__log2f(x) * LN2F, -100.0f);
  pc += ispos ? 1u : 0u;
  nc += isneg ? 1u : 0u;
  psumf += ispos ? loss : 0.0f;
  unsigned b = isneg ? (__float_as_uint(loss) >> 19) : (NBINS1 + ln);
  atomicAdd(&hc[b], 1u);
}

// ---------------- Kernel 1: reductions + level-1 histogram -----------------
// Hot loop: R18 dg_kb1 byte-for-byte (literal bounds). Do not touch.
extern "C" __global__ void __launch_bounds__(256, 4)
k1_hist(const float* __restrict__ pred, const float* __restrict__ gt,
        const float* __restrict__ mask, unsigned* __restrict__ hist1,
        Ctrl* __restrict__ ctrl, int n4, int n) {
  __shared__ unsigned h[NBINS1 + 64];
  for (int i = threadIdx.x; i < NBINS1 + 64; i += blockDim.x) h[i] = 0u;
  __syncthreads();

  const float4* p4 = (const float4*)pred;
  const float4* g4 = (const float4*)gt;
  const float4* m4 = (const float4*)mask;
  int gtid = blockIdx.x * blockDim.x + threadIdx.x;
  int S = gridDim.x * blockDim.x;
  unsigned ln = threadIdx.x & 63;

  unsigned pc = 0, nc = 0;
  float psumf = 0.0f;
  for (int rep = 0; rep < 1; ++rep) {
    for (int i = gtid; i + 3 * S + 1 < n4; i += 4 * S) {
      int jb = i + rep;
      float4 pv0 = p4[jb], pv1 = p4[jb + S], pv2 = p4[jb + 2 * S], pv3 = p4[jb + 3 * S];
      float4 gv0 = g4[jb], gv1 = g4[jb + S], gv2 = g4[jb + 2 * S], gv3 = g4[jb + 3 * S];
      float4 mv0 = m4[jb], mv1 = m4[jb + S], mv2 = m4[jb + 2 * S], mv3 = m4[jb + 3 * S];
      float pa[16] = {pv0.x, pv0.y, pv0.z, pv0.w, pv1.x, pv1.y, pv1.z, pv1.w,
                      pv2.x, pv2.y, pv2.z, pv2.w, pv3.x, pv3.y, pv3.z, pv3.w};
      float ga[16] = {gv0.x, gv0.y, gv0.z, gv0.w, gv1.x, gv1.y, gv1.z, gv1.w,
                      gv2.x, gv2.y, gv2.z, gv2.w, gv3.x, gv3.y, gv3.z, gv3.w};
      float ma[16] = {mv0.x, mv0.y, mv0.z, mv0.w, mv1.x, mv1.y, mv1.z, mv1.w,
                      mv2.x, mv2.y, mv2.z, mv2.w, mv3.x, mv3.y, mv3.z, mv3.w};
#pragma unroll
      for (int j = 0; j < 16; j++) {
        bool gpos = (ga[j] != 0.0f);
        bool valid = (ma[j] != 0.0f);
        bool ispos = valid && gpos;
        bool isneg = valid && !gpos;
        float x = gpos ? pa[j] : 1.0f - pa[j];
        float loss = -fmaxf(__log2f(x) * LN2F, -100.0f);
        pc += ispos ? 1u : 0u;
        nc += isneg ? 1u : 0u;
        psumf += ispos ? loss : 0.0f;
        unsigned b = isneg ? (__float_as_uint(loss) >> 19) : (NBINS1 + ln);
        atomicAdd(&h[b], 1u);   // unconditional: no exec-mask branch
      }
    }
  }

  // ---- cold coverage completion (<=1 iter/thread; branchless proc1) ----
  // main nest covered {gtid + 4kS : gtid + 4kS + 3S + 1 < n4}, i.e. this
  // thread's stride class below idone; finish [idone, n4) and the n%4 tail.
  int idone = gtid;
  while (idone + 3 * S + 1 < n4) idone += 4 * S;
  for (int i = idone; i < n4; i += S) {
    float4 pv = p4[i], gv = g4[i], mv = m4[i];
    proc1(pv.x, gv.x, mv.x, ln, pc, nc, psumf, h);
    proc1(pv.y, gv.y, mv.y, ln, pc, nc, psumf, h);
    proc1(pv.z, gv.z, mv.z, ln, pc, nc, psumf, h);
    proc1(pv.w, gv.w, mv.w, ln, pc, nc, psumf, h);
  }
  for (int t = n4 * 4 + gtid; t < n; t += S) {
    proc1(pred[t], gt[t], mask[t], ln, pc, nc, psumf, h);
  }

  // ---- light epilogue (k1b-shaped): wave reduce -> per-wave global atomics
  unsigned long long pcl = pc, ncl = nc;
  double psum = (double)psumf;
  for (int off = 32; off > 0; off >>= 1) {
    pcl += __shfl_down(pcl, off);
    ncl += __shfl_down(ncl, off);
    psum += __shfl_down(psum, off);
  }
  if (ln == 0) {
    atomicAdd(&ctrl->pos_cnt, pcl);
    atomicAdd(&ctrl->neg_cnt, ncl);
    unsafeAtomicAdd(&ctrl->pos_sum, psum);
  }
  __syncthreads();   // all LDS histogram atomics complete
  // flush LDS histogram to global (dummy bins >= NBINS1 ignored)
  for (int b = threadIdx.x; b < NBINS1; b += blockDim.x) {
    unsigned c = h[b];
    if (c) atomicAdd(&hist1[b], c);
  }
}

// ---------- Kernel 5: select + midpoint neg_sum + output (1 block) ---------
extern "C" __global__ void __launch_bounds__(256)
k5_final(const unsigned* __restrict__ hist1, Ctrl* __restrict__ ctrl,
         float* __restrict__ out) {
  const int T = 256, CH = NBINS1 / T;  // 16 bins per thread
  __shared__ unsigned long long sarr[T];
  __shared__ unsigned long long sk;
  __shared__ unsigned sB, skrem;
  __shared__ double sred[4];
  int t = threadIdx.x;
  int wv = t >> 6, ln = t & 63;

  unsigned cnt[CH];
  unsigned long long tot = 0;
  for (int j = 0; j < CH; j++) { cnt[j] = hist1[t * CH + j]; tot += cnt[j]; }
  sarr[t] = tot;
  if (t == 0) {
    sB = 0xFFFFFFFFu; skrem = 0u;
    unsigned long long pos = ctrl->pos_cnt, negtot = ctrl->neg_cnt;
    unsigned long long k = 0;
    if (pos > 0) {               // FALLBACK_NEG=0 when pos==0
      k = pos * 3ull;            // floor(pos*3.0), exact in integer
      if (k > negtot) k = negtot;
    }
    ctrl->k = k;
    sk = k;
  }
  __syncthreads();
  // inclusive suffix scan: sarr[t] = sum over threads >= t
  for (int off = 1; off < T; off <<= 1) {
    unsigned long long v = (t + off < T) ? sarr[t + off] : 0ull;
    __syncthreads();
    sarr[t] += v;
    __syncthreads();
  }
  unsigned long long k = sk;
  if (k > 0) {
    unsigned long long above = sarr[t] - tot;
    if (above < k && sarr[t] >= k) {
      unsigned long long cum = above;
      for (int j = CH - 1; j >= 0; j--) {
        if (cum + (unsigned long long)cnt[j] >= k) {
          sB = (unsigned)(t * CH + j);
          skrem = (unsigned)(k - cum);
          break;
        }
        cum += cnt[j];
      }
    }
  }
  __syncthreads();
  unsigned B = sB;

  // neg_sum (midpoint model): each thread sums its own bins above B
  double s = 0.0;
  if (B != 0xFFFFFFFFu) {
    for (int j = 0; j < CH; j++) {
      unsigned bi = (unsigned)(t * CH + j);
      if (bi > B && cnt[j]) s += (double)cnt[j] * bin_mid(bi);
    }
  }
  for (int off = 32; off > 0; off >>= 1) s += __shfl_down(s, off);
  if (ln == 0) sred[wv] = s;
  __syncthreads();
  if (t == 0) {
    double neg_sum = sred[0] + sred[1] + sred[2] + sred[3];
    if (skrem > 0 && B != 0xFFFFFFFFu)
      neg_sum += (double)skrem * bin_mid(B);
    double denom = (double)ctrl->pos_cnt + (double)k + 1e-6;
    out[0] = (float)((ctrl->pos_sum + neg_sum) / denom);
  }
}

// ---------------------------------------------------------------------------
extern "C" void kernel_launch(void* const* d_in, const int* in_sizes, int n_in,
                              void* d_out, int out_size, void* d_ws, size_t ws_size,
                              hipStream_t stream) {
  const float* pred = (const float*)d_in[0];
  const float* gt   = (const float*)d_in[1];
  const float* mask = (const float*)d_in[2];
  float* out = (float*)d_out;
  int n = in_sizes[0];
  int n4 = n / 4;
  char* ws = (char*)d_ws;

  // layout: ctrl@0 (64B), hist1@256 (16KB) -> zero first 16640 bytes
  const size_t HIST1_OFF = 256;
  const size_t ZERO_BYTES = HIST1_OFF + NBINS1 * sizeof(unsigned);   // 16640

  Ctrl* ctrl = (Ctrl*)ws;
  unsigned* hist1 = (unsigned*)(ws + HIST1_OFF);

  hipMemsetAsync(d_ws, 0, ZERO_BYTES, stream);
  k1_hist<<<K1_BLOCKS, 256, 0, stream>>>(pred, gt, mask, hist1, ctrl, n4, n);
  k5_final<<<1, 256, 0, stream>>>(hist1, ctrl, out);
}

// Round 10
// 181.355 us; speedup vs baseline: 1.7821x; 1.6201x over previous
//
#include <hip/hip_runtime.h>
#include <math.h>

// MaskedBalancedBCELoss — hard-negative mining via count-histogram select.
//
// R20: make production k1 BYTE-SHAPED like the proven-fast dg_kb1 and move
// everything else out of the kernel. Codegen ledger (same math, same grid):
//   R16 k1b  (arrays, literal bounds, no tails, f32-store epi): 24.7us/pass
//   R18 dg_kb1 (same, AREP=1)                                 : ~39us
//   R18/R19 k1 (same loop + tails + u64/f64 ctrl atomics)     : 174/178us
//   R17 k1  (no arrays, branchless atomic, tails)             : 70.8us
// The hot loop's schedule survives ONLY when the kernel contains nothing
// but: literal-bound array loop + unconditional LDS atomic + f32 shuffle
// reduce + one plain store per wave + hist flush. So:
//   * host picks b = largest blocks in [256,1024] with n4 % (b*1024)==0
//     -> for 32x640x640: b=800, 4-step loop covers [0,n4) EXACTLY,
//     4 iters/thread, NO tail code at all in k1.
//   * per-wave partials (pc,nc,psum) as f32 (exact: <=4096 counts/wave)
//     stored as one plain float4 per wave -> wredux[]. No Ctrl struct.
//   * k5 pre-reduces wredux in f64 (exact), then unchanged select.
//   * generic n (no clean divisor / n%4): cold k2_tail kernel covers the
//     leftover range; never launched for this problem's shape.

#define NBINS1 4096

#define LN2F 0.69314718055994530942f

__device__ __forceinline__ double bin_mid(unsigned b) {
  return (double)__uint_as_float((b << 19) | 0x40000u);
}

// Branchless per-element processing (loss bit-identical to R10..R19).
__device__ __forceinline__ void proc1(float p, float g, float m, unsigned ln,
                                      unsigned& pc, unsigned& nc,
                                      float& psumf, unsigned* __restrict__ hc) {
  bool gpos = (g != 0.0f);
  bool valid = (m != 0.0f);
  bool ispos = valid && gpos;
  bool isneg = valid && !gpos;
  float x = gpos ? p : 1.0f - p;
  float loss = -fmaxf(__log2f(x) * LN2F, -100.0f);
  pc += ispos ? 1u : 0u;
  nc += isneg ? 1u : 0u;
  psumf += ispos ? loss : 0.0f;
  unsigned b = isneg ? (__float_as_uint(loss) >> 19) : (NBINS1 + ln);
  atomicAdd(&hc[b], 1u);
}

// ---------------- Kernel 1: dg_kb1-shaped hot kernel -----------------------
// Covers [0, nfull4) float4s exactly (host guarantees nfull4 % (4*S) == 0).
// NOTHING else lives in this kernel. Do not add code here.
extern "C" __global__ void __launch_bounds__(256, 4)
k1_hist(const float* __restrict__ pred, const float* __restrict__ gt,
        const float* __restrict__ mask, unsigned* __restrict__ hist1,
        float4* __restrict__ wredux, int nfull4) {
  __shared__ unsigned h[NBINS1 + 64];
  for (int i = threadIdx.x; i < NBINS1 + 64; i += blockDim.x) h[i] = 0u;
  __syncthreads();

  const float4* p4 = (const float4*)pred;
  const float4* g4 = (const float4*)gt;
  const float4* m4 = (const float4*)mask;
  int gtid = blockIdx.x * blockDim.x + threadIdx.x;
  int S = gridDim.x * blockDim.x;
  unsigned ln = threadIdx.x & 63;

  unsigned pc = 0, nc = 0;
  float psumf = 0.0f;
  for (int rep = 0; rep < 1; ++rep) {
    for (int i = gtid; i + 3 * S < nfull4; i += 4 * S) {
      int jb = i + rep;
      float4 pv0 = p4[jb], pv1 = p4[jb + S], pv2 = p4[jb + 2 * S], pv3 = p4[jb + 3 * S];
      float4 gv0 = g4[jb], gv1 = g4[jb + S], gv2 = g4[jb + 2 * S], gv3 = g4[jb + 3 * S];
      float4 mv0 = m4[jb], mv1 = m4[jb + S], mv2 = m4[jb + 2 * S], mv3 = m4[jb + 3 * S];
      float pa[16] = {pv0.x, pv0.y, pv0.z, pv0.w, pv1.x, pv1.y, pv1.z, pv1.w,
                      pv2.x, pv2.y, pv2.z, pv2.w, pv3.x, pv3.y, pv3.z, pv3.w};
      float ga[16] = {gv0.x, gv0.y, gv0.z, gv0.w, gv1.x, gv1.y, gv1.z, gv1.w,
                      gv2.x, gv2.y, gv2.z, gv2.w, gv3.x, gv3.y, gv3.z, gv3.w};
      float ma[16] = {mv0.x, mv0.y, mv0.z, mv0.w, mv1.x, mv1.y, mv1.z, mv1.w,
                      mv2.x, mv2.y, mv2.z, mv2.w, mv3.x, mv3.y, mv3.z, mv3.w};
#pragma unroll
      for (int j = 0; j < 16; j++) {
        bool gpos = (ga[j] != 0.0f);
        bool valid = (ma[j] != 0.0f);
        bool ispos = valid && gpos;
        bool isneg = valid && !gpos;
        float x = gpos ? pa[j] : 1.0f - pa[j];
        float loss = -fmaxf(__log2f(x) * LN2F, -100.0f);
        pc += ispos ? 1u : 0u;
        nc += isneg ? 1u : 0u;
        psumf += ispos ? loss : 0.0f;
        unsigned b = isneg ? (__float_as_uint(loss) >> 19) : (NBINS1 + ln);
        atomicAdd(&h[b], 1u);   // unconditional: no exec-mask branch
      }
    }
  }

  // epilogue, dg_kb1-shaped: f32 shuffle reduce + ONE plain store per wave.
  // counts <= 4096/wave -> exact in f32.
  float fpc = (float)pc, fnc = (float)nc;
  for (int off = 32; off > 0; off >>= 1) {
    fpc += __shfl_down(fpc, off);
    fnc += __shfl_down(fnc, off);
    psumf += __shfl_down(psumf, off);
  }
  if (ln == 0)
    wredux[blockIdx.x * 4 + (threadIdx.x >> 6)] = make_float4(fpc, fnc, psumf, 0.0f);
  __syncthreads();   // all LDS histogram atomics complete
  for (int b = threadIdx.x; b < NBINS1; b += blockDim.x) {
    unsigned c = h[b];
    if (c) atomicAdd(&hist1[b], c);
  }
}

// -------- k2_tail: cold coverage for generic n (NOT launched when the ------
// divisor search succeeds and n%4==0, i.e. never for 32x640x640).
extern "C" __global__ void __launch_bounds__(256, 4)
k2_tail(const float* __restrict__ pred, const float* __restrict__ gt,
        const float* __restrict__ mask, unsigned* __restrict__ hist1,
        float4* __restrict__ wredux, int start4, int n4, int n, int wbase) {
  __shared__ unsigned h[NBINS1 + 64];
  for (int i = threadIdx.x; i < NBINS1 + 64; i += blockDim.x) h[i] = 0u;
  __syncthreads();

  const float4* p4 = (const float4*)pred;
  const float4* g4 = (const float4*)gt;
  const float4* m4 = (const float4*)mask;
  int gtid = blockIdx.x * blockDim.x + threadIdx.x;
  int S = gridDim.x * blockDim.x;
  unsigned ln = threadIdx.x & 63;

  unsigned pc = 0, nc = 0;
  float psumf = 0.0f;
  for (int i = start4 + gtid; i < n4; i += S) {
    float4 pv = p4[i], gv = g4[i], mv = m4[i];
    proc1(pv.x, gv.x, mv.x, ln, pc, nc, psumf, h);
    proc1(pv.y, gv.y, mv.y, ln, pc, nc, psumf, h);
    proc1(pv.z, gv.z, mv.z, ln, pc, nc, psumf, h);
    proc1(pv.w, gv.w, mv.w, ln, pc, nc, psumf, h);
  }
  for (int t = n4 * 4 + gtid; t < n; t += S) {
    proc1(pred[t], gt[t], mask[t], ln, pc, nc, psumf, h);
  }

  float fpc = (float)pc, fnc = (float)nc;
  for (int off = 32; off > 0; off >>= 1) {
    fpc += __shfl_down(fpc, off);
    fnc += __shfl_down(fnc, off);
    psumf += __shfl_down(psumf, off);
  }
  if (ln == 0)
    wredux[wbase + blockIdx.x * 4 + (threadIdx.x >> 6)] = make_float4(fpc, fnc, psumf, 0.0f);
  __syncthreads();
  for (int b = threadIdx.x; b < NBINS1; b += blockDim.x) {
    unsigned c = h[b];
    if (c) atomicAdd(&hist1[b], c);
  }
}

// ---------- Kernel 5: wredux reduce + select + midpoint neg_sum ------------
extern "C" __global__ void __launch_bounds__(256)
k5_final(const unsigned* __restrict__ hist1, const float4* __restrict__ wredux,
         int nwaves, float* __restrict__ out) {
  const int T = 256, CH = NBINS1 / T;  // 16 bins per thread
  __shared__ unsigned long long sarr[T];
  __shared__ unsigned long long sk;
  __shared__ unsigned sB, skrem;
  __shared__ double sred[4];
  __shared__ double rpc[T], rnc[T], rps[T];
  __shared__ unsigned long long s_pos;
  __shared__ double s_psum;
  int t = threadIdx.x;
  int wv = t >> 6, ln = t & 63;

  // ---- reduce per-wave partials (exact: counts are integers in f32) ----
  double tpc = 0.0, tnc = 0.0, tps = 0.0;
  for (int i = t; i < nwaves; i += T) {
    float4 v = wredux[i];
    tpc += (double)v.x; tnc += (double)v.y; tps += (double)v.z;
  }
  rpc[t] = tpc; rnc[t] = tnc; rps[t] = tps;
  __syncthreads();
  for (int off = T / 2; off > 0; off >>= 1) {
    if (t < off) { rpc[t] += rpc[t + off]; rnc[t] += rnc[t + off]; rps[t] += rps[t + off]; }
    __syncthreads();
  }

  unsigned cnt[CH];
  unsigned long long tot = 0;
  for (int j = 0; j < CH; j++) { cnt[j] = hist1[t * CH + j]; tot += cnt[j]; }
  sarr[t] = tot;
  if (t == 0) {
    sB = 0xFFFFFFFFu; skrem = 0u;
    unsigned long long pos = (unsigned long long)(rpc[0] + 0.5);
    unsigned long long negtot = (unsigned long long)(rnc[0] + 0.5);
    unsigned long long k = 0;
    if (pos > 0) {               // FALLBACK_NEG=0 when pos==0
      k = pos * 3ull;            // floor(pos*3.0), exact in integer
      if (k > negtot) k = negtot;
    }
    sk = k;
    s_pos = pos;
    s_psum = rps[0];
  }
  __syncthreads();
  // inclusive suffix scan: sarr[t] = sum over threads >= t
  for (int off = 1; off < T; off <<= 1) {
    unsigned long long v = (t + off < T) ? sarr[t + off] : 0ull;
    __syncthreads();
    sarr[t] += v;
    __syncthreads();
  }
  unsigned long long k = sk;
  if (k > 0) {
    unsigned long long above = sarr[t] - tot;
    if (above < k && sarr[t] >= k) {
      unsigned long long cum = above;
      for (int j = CH - 1; j >= 0; j--) {
        if (cum + (unsigned long long)cnt[j] >= k) {
          sB = (unsigned)(t * CH + j);
          skrem = (unsigned)(k - cum);
          break;
        }
        cum += cnt[j];
      }
    }
  }
  __syncthreads();
  unsigned B = sB;

  // neg_sum (midpoint model): each thread sums its own bins above B
  double s = 0.0;
  if (B != 0xFFFFFFFFu) {
    for (int j = 0; j < CH; j++) {
      unsigned bi = (unsigned)(t * CH + j);
      if (bi > B && cnt[j]) s += (double)cnt[j] * bin_mid(bi);
    }
  }
  for (int off = 32; off > 0; off >>= 1) s += __shfl_down(s, off);
  if (ln == 0) sred[wv] = s;
  __syncthreads();
  if (t == 0) {
    double neg_sum = sred[0] + sred[1] + sred[2] + sred[3];
    if (skrem > 0 && B != 0xFFFFFFFFu)
      neg_sum += (double)skrem * bin_mid(B);
    double denom = (double)s_pos + (double)k + 1e-6;
    out[0] = (float)((s_psum + neg_sum) / denom);
  }
}

// ---------------------------------------------------------------------------
extern "C" void kernel_launch(void* const* d_in, const int* in_sizes, int n_in,
                              void* d_out, int out_size, void* d_ws, size_t ws_size,
                              hipStream_t stream) {
  const float* pred = (const float*)d_in[0];
  const float* gt   = (const float*)d_in[1];
  const float* mask = (const float*)d_in[2];
  float* out = (float*)d_out;
  int n = in_sizes[0];
  int n4 = n / 4;
  char* ws = (char*)d_ws;

  // grid choice: largest b in [256,1024] with n4 % (b*1024) == 0 gives
  // EXACT coverage (4 iters/thread, no tail kernel). 32x640x640 -> b=800.
  int b = 0;
  for (int cand = 1024; cand >= 256; --cand) {
    if (n4 % (cand * 1024) == 0) { b = cand; break; }
  }
  int nfull4, need_tail;
  if (b > 0) {
    nfull4 = n4;
    need_tail = (n & 3) != 0;
  } else {
    b = 1024;
    nfull4 = (n4 / (b * 1024)) * (b * 1024);
    need_tail = 1;
  }
  const int TAILB = 256;
  int nwaves = b * 4 + (need_tail ? TAILB * 4 : 0);

  // layout: hist1@256 (16KB) -> zero first 16640B; wredux@64KB (<=80KB)
  const size_t HIST1_OFF = 256;
  const size_t ZERO_BYTES = HIST1_OFF + NBINS1 * sizeof(unsigned);   // 16640
  const size_t WREDUX_OFF = 64 * 1024;

  unsigned* hist1 = (unsigned*)(ws + HIST1_OFF);
  float4* wredux = (float4*)(ws + WREDUX_OFF);

  hipMemsetAsync(d_ws, 0, ZERO_BYTES, stream);
  k1_hist<<<b, 256, 0, stream>>>(pred, gt, mask, hist1, wredux, nfull4);
  if (need_tail) {
    k2_tail<<<TAILB, 256, 0, stream>>>(pred, gt, mask, hist1, wredux,
                                       nfull4, n4, n, b * 4);
  }
  k5_final<<<1, 256, 0, stream>>>(hist1, wredux, nwaves, out);
}